// Round 19
// baseline (859.602 us; speedup 1.0000x reference)
//
#include <hip/hip_runtime.h>
#include <math.h>

#define NN 100000
#define NE 1600000
#define D 64
#define DE 32
#define NB_SCAN ((NN + 255) / 256)   // 391

typedef __attribute__((ext_vector_type(8))) short short8;
typedef __attribute__((ext_vector_type(4))) float f32x4;

__device__ __forceinline__ int rfl(int v){ return __builtin_amdgcn_readfirstlane(v); }

#define LEAKY(v) fmaxf((v), 0.2f*(v))

__device__ __forceinline__ unsigned short f2bf(float x){
  unsigned u = __float_as_uint(x);
  unsigned r = (u + 0x7fffu + ((u >> 16) & 1u)) >> 16;
  return (unsigned short)r;
}
__device__ __forceinline__ float bf2f(unsigned short b){
  return __uint_as_float(((unsigned)b) << 16);
}

// deg accumulate AND per-edge rank harvest (coalesced rank write).
__global__ __launch_bounds__(256) void k_deg(const int* __restrict__ dst, int* __restrict__ cursor,
                                             int* __restrict__ rank){
  int i = blockIdx.x*256 + threadIdx.x;
  if (i < NE) rank[i] = atomicAdd(&cursor[dst[i]], 1);
}

// histogram of degrees (clamped to 255)
__global__ __launch_bounds__(256) void k_hist(const int* __restrict__ deg, int* __restrict__ hist){
  int n = blockIdx.x*256 + threadIdx.x;
  if (n < NN) atomicAdd(&hist[min(deg[n], 255)], 1);
}

// exclusive scan over 256 bins -> binoff & bincur
__global__ __launch_bounds__(256) void k_binscan(const int* __restrict__ hist,
                                                 int* __restrict__ binoff, int* __restrict__ bincur){
  __shared__ int tmp[256];
  int tid = threadIdx.x;
  int v = hist[tid];
  tmp[tid] = v;
  __syncthreads();
  for (int off = 1; off < 256; off <<= 1){
    int t = (tid >= off) ? tmp[tid-off] : 0;
    __syncthreads();
    tmp[tid] += t;
    __syncthreads();
  }
  int excl = tmp[tid] - v;
  binoff[tid] = excl;
  bincur[tid] = excl;
}

// place nodes into degree-sorted order: perm[sortpos]=n, nrank[n]=sortpos, degs[sortpos]=deg
__global__ __launch_bounds__(256) void k_sort(const int* __restrict__ deg, int* __restrict__ bincur,
                                              int* __restrict__ perm, int* __restrict__ nrank,
                                              int* __restrict__ degs){
  int n = blockIdx.x*256 + threadIdx.x;
  if (n < NN){
    int d = deg[n];
    int sp = atomicAdd(&bincur[min(d, 255)], 1);
    perm[sp] = n;
    nrank[n] = sp;
    degs[sp] = d;
  }
}

__global__ __launch_bounds__(256) void k_scan_a(const int* __restrict__ deg, int* __restrict__ bsum){
  __shared__ int sh[256];
  int tid = threadIdx.x;
  int i = blockIdx.x*256 + tid;
  sh[tid] = (i < NN) ? deg[i] : 0;
  __syncthreads();
  for (int s = 128; s > 0; s >>= 1){
    if (tid < s) sh[tid] += sh[tid+s];
    __syncthreads();
  }
  if (tid == 0) bsum[blockIdx.x] = sh[0];
}

__global__ __launch_bounds__(512) void k_scan_b(int* __restrict__ bsum, int* __restrict__ rowptr){
  __shared__ int tmp[512];
  int tid = threadIdx.x;
  int v = (tid < NB_SCAN) ? bsum[tid] : 0;
  tmp[tid] = v;
  __syncthreads();
  for (int off = 1; off < 512; off <<= 1){
    int t = (tid >= off) ? tmp[tid-off] : 0;
    __syncthreads();
    tmp[tid] += t;
    __syncthreads();
  }
  if (tid < NB_SCAN) bsum[tid] = tmp[tid] - v;
  if (tid == 511) rowptr[NN] = tmp[511];
}

// rowptr over SORTED degs (degs[] indexed by sorted position)
__global__ __launch_bounds__(256) void k_scan_c(const int* bsum, int* rowptr, const int* degs){
  __shared__ int tmp[256];
  int tid = threadIdx.x;
  int i = blockIdx.x*256 + tid;
  int v = (i < NN) ? degs[i] : 0;
  tmp[tid] = v;
  __syncthreads();
  for (int off = 1; off < 256; off <<= 1){
    int t = (tid >= off) ? tmp[tid-off] : 0;
    __syncthreads();
    tmp[tid] += t;
    __syncthreads();
  }
  if (i < NN){
    rowptr[i] = tmp[tid] - v + bsum[blockIdx.x];
  }
}

// Atomic-free scatter into SORTED CSR: pos = rowptr[nrank[dst]] + rank.
// R15-proven block-cooperative payload copy (coalesced reads, 64B bf16 row writes).
__global__ __launch_bounds__(256) void k_scatter(const int* __restrict__ srcp, const int* __restrict__ dstp,
                                                 const int* __restrict__ rank, const int* __restrict__ nrank,
                                                 const int* __restrict__ rowptr,
                                                 const float4* __restrict__ eattr4,
                                                 int* __restrict__ ssrc,
                                                 unsigned short* __restrict__ ea_csr){
  __shared__ int spos[256];
  int tid = threadIdx.x;
  int i = blockIdx.x*256 + tid;
  int pos = 0;
  if (i < NE){
    int d = dstp[i];
    pos = rowptr[nrank[d]] + rank[i];
    ssrc[pos] = srcp[i];
  }
  spos[tid] = pos;
  __syncthreads();
  int chunk = tid & 7;
  int rbase = blockIdx.x*256;
  #pragma unroll
  for (int k = 0; k < 8; ++k){
    int rl = (tid >> 3) + 32*k;
    int r = rbase + rl;
    if (r < NE){
      float4 v = eattr4[(size_t)r*8 + chunk];
      ushort4 o;
      o.x = f2bf(v.x); o.y = f2bf(v.y); o.z = f2bf(v.z); o.w = f2bf(v.w);
      *(ushort4*)(ea_csr + (size_t)spos[rl]*DE + chunk*4) = o;
    }
  }
}

// MFMA linear: xl[n][j] = bf16( b[j] + sum_k x[n][k]*W[k][j] ).
__global__ __launch_bounds__(256) void k_lin(const float* __restrict__ xin, const float* __restrict__ W,
                                             const float* __restrict__ b, unsigned short* __restrict__ xl){
  int lane = threadIdx.x & 63;
  int q = lane & 15, g = lane >> 4;
  int wid = blockIdx.x*(blockDim.x>>6) + (threadIdx.x>>6);
  int nw = gridDim.x*(blockDim.x>>6);
  short8 wb[2][4];
  #pragma unroll
  for (int kk = 0; kk < 2; ++kk)
    #pragma unroll
    for (int j = 0; j < 4; ++j)
      #pragma unroll
      for (int i = 0; i < 8; ++i)
        wb[kk][j][i] = (short)f2bf(W[(32*kk + 8*g + i)*D + 4*q + j]);
  float4 b4 = *(const float4*)(b + 4*q);
  for (int t0 = wid; t0 < NN/16; t0 += nw){
    int n0 = rfl(t0)*16;
    const float* xr = xin + (size_t)(n0 + q)*D + 8*g;
    float4 a0 = *(const float4*)(xr);
    float4 a1 = *(const float4*)(xr + 4);
    float4 a2 = *(const float4*)(xr + 32);
    float4 a3 = *(const float4*)(xr + 36);
    short8 af0, af1;
    af0[0]=(short)f2bf(a0.x); af0[1]=(short)f2bf(a0.y); af0[2]=(short)f2bf(a0.z); af0[3]=(short)f2bf(a0.w);
    af0[4]=(short)f2bf(a1.x); af0[5]=(short)f2bf(a1.y); af0[6]=(short)f2bf(a1.z); af0[7]=(short)f2bf(a1.w);
    af1[0]=(short)f2bf(a2.x); af1[1]=(short)f2bf(a2.y); af1[2]=(short)f2bf(a2.z); af1[3]=(short)f2bf(a2.w);
    af1[4]=(short)f2bf(a3.x); af1[5]=(short)f2bf(a3.y); af1[6]=(short)f2bf(a3.z); af1[7]=(short)f2bf(a3.w);
    f32x4 acc0 = {b4.x, b4.x, b4.x, b4.x};
    f32x4 acc1 = {b4.y, b4.y, b4.y, b4.y};
    f32x4 acc2 = {b4.z, b4.z, b4.z, b4.z};
    f32x4 acc3 = {b4.w, b4.w, b4.w, b4.w};
    acc0 = __builtin_amdgcn_mfma_f32_16x16x32_bf16(af0, wb[0][0], acc0, 0, 0, 0);
    acc1 = __builtin_amdgcn_mfma_f32_16x16x32_bf16(af0, wb[0][1], acc1, 0, 0, 0);
    acc2 = __builtin_amdgcn_mfma_f32_16x16x32_bf16(af0, wb[0][2], acc2, 0, 0, 0);
    acc3 = __builtin_amdgcn_mfma_f32_16x16x32_bf16(af0, wb[0][3], acc3, 0, 0, 0);
    acc0 = __builtin_amdgcn_mfma_f32_16x16x32_bf16(af1, wb[1][0], acc0, 0, 0, 0);
    acc1 = __builtin_amdgcn_mfma_f32_16x16x32_bf16(af1, wb[1][1], acc1, 0, 0, 0);
    acc2 = __builtin_amdgcn_mfma_f32_16x16x32_bf16(af1, wb[1][2], acc2, 0, 0, 0);
    acc3 = __builtin_amdgcn_mfma_f32_16x16x32_bf16(af1, wb[1][3], acc3, 0, 0, 0);
    #pragma unroll
    for (int i = 0; i < 4; ++i){
      ushort4 pk;
      pk.x = f2bf(acc0[i]); pk.y = f2bf(acc1[i]); pk.z = f2bf(acc2[i]); pk.w = f2bf(acc3[i]);
      *(ushort4*)(xl + (size_t)(n0 + 4*g + i)*D + 4*q) = pk;
    }
  }
}

// Fused layer over SORTED node order: wave w owns sorted slots 4w..4w+3
// (equal-degree nodes -> minimal tile padding). CSR reads sequential;
// node identity only at xd load and out write (perm[slot]).
__global__ __launch_bounds__(256) void k_node(const int* __restrict__ rowptr,
                                              const int* __restrict__ perm,
                                              const int* __restrict__ ssrc,
                                              const unsigned short* __restrict__ ea_csr,
                                              const float* __restrict__ We,
                                              const float* __restrict__ att,
                                              const unsigned short* __restrict__ xl,
                                              const float* __restrict__ bias,
                                              float* __restrict__ outp){
  int lane = threadIdx.x & 63;
  int q = lane & 15, g = lane >> 4;
  int wid = blockIdx.x*(blockDim.x>>6) + (threadIdx.x>>6);
  int n0 = wid*4;                       // sorted slots; 25000 waves x 4
  if (n0 >= NN) return;
  short8 wb[4];
  #pragma unroll
  for (int j = 0; j < 4; ++j)
    #pragma unroll
    for (int i = 0; i < 8; ++i)
      wb[j][i] = (short)f2bf(We[(8*g + i)*D + 4*q + j]);
  float4 att4 = *(const float4*)(att + 4*q);
  float4 bi4  = *(const float4*)(bias + 4*q);
  int node_g = perm[n0 + g];
  int st_g = rowptr[n0 + g], en_g = rowptr[n0 + g + 1];
  int anode = q >> 2, aoff = q & 3;
  int st_a = rowptr[n0 + anode], en_a = rowptr[n0 + anode + 1];
  int deg = en_g - st_g;
  int dmax = max(deg, __shfl_xor(deg, 16, 64));
  dmax = max(dmax, __shfl_xor(dmax, 32, 64));
  int ntile = (dmax + 3) >> 2;
  ushort4 xdu = *(const ushort4*)(xl + (size_t)node_g*D + 4*q);
  float xd0 = bf2f(xdu.x), xd1 = bf2f(xdu.y), xd2 = bf2f(xdu.z), xd3 = bf2f(xdu.w);
  float den = 0.f;
  float ac0=0.f, ac1=0.f, ac2=0.f, ac3=0.f;
  float ts0=0.f, ts1=0.f, ts2=0.f, ts3=0.f;

#define LOAD_A(T, DST) { int apos_ = st_a + (T)*4 + aoff; \
  int arow_ = (apos_ < en_a) ? apos_ : ((en_a > st_a) ? (en_a - 1) : 0); \
  DST = *(const short8*)(ea_csr + (size_t)arow_*DE + 8*g); }
#define LOAD_S(T, S0,S1,S2,S3) { int b_ = st_g + (T)*4; \
  S0 = ssrc[(b_   < en_g) ? b_   : 0]; S1 = ssrc[(b_+1 < en_g) ? b_+1 : 0]; \
  S2 = ssrc[(b_+2 < en_g) ? b_+2 : 0]; S3 = ssrc[(b_+3 < en_g) ? b_+3 : 0]; }
#define LOAD_X(S0,S1,S2,S3, X0,X1,X2,X3) { \
  X0 = *(const ushort4*)(xl + (size_t)S0*D + 4*q); \
  X1 = *(const ushort4*)(xl + (size_t)S1*D + 4*q); \
  X2 = *(const ushort4*)(xl + (size_t)S2*D + 4*q); \
  X3 = *(const ushort4*)(xl + (size_t)S3*D + 4*q); }

  short8 aC = {0,0,0,0,0,0,0,0};
  int s0C=0, s1C=0, s2C=0, s3C=0;
  ushort4 x0C={0,0,0,0}, x1C={0,0,0,0}, x2C={0,0,0,0}, x3C={0,0,0,0};
  if (ntile > 0){
    LOAD_A(0, aC);
    LOAD_S(0, s0C, s1C, s2C, s3C);
    LOAD_X(s0C, s1C, s2C, s3C, x0C, x1C, x2C, x3C);
  }
  for (int t = 0; t < ntile; ++t){
    short8 aN = aC;
    int s0N=s0C, s1N=s1C, s2N=s2C, s3N=s3C;
    ushort4 x0N=x0C, x1N=x1C, x2N=x2C, x3N=x3C;
    if (t + 1 < ntile){
      LOAD_A(t+1, aN);
      LOAD_S(t+1, s0N, s1N, s2N, s3N);
      LOAD_X(s0N, s1N, s2N, s3N, x0N, x1N, x2N, x3N);
    }
    __builtin_amdgcn_s_setprio(1);
    f32x4 d0={0.f,0.f,0.f,0.f}, d1={0.f,0.f,0.f,0.f}, d2={0.f,0.f,0.f,0.f}, d3={0.f,0.f,0.f,0.f};
    d0 = __builtin_amdgcn_mfma_f32_16x16x32_bf16(aC, wb[0], d0, 0, 0, 0);
    d1 = __builtin_amdgcn_mfma_f32_16x16x32_bf16(aC, wb[1], d1, 0, 0, 0);
    d2 = __builtin_amdgcn_mfma_f32_16x16x32_bf16(aC, wb[2], d2, 0, 0, 0);
    d3 = __builtin_amdgcn_mfma_f32_16x16x32_bf16(aC, wb[3], d3, 0, 0, 0);
    __builtin_amdgcn_s_setprio(0);
    #pragma unroll
    for (int i = 0; i < 4; ++i){
      int e = st_g + t*4 + i;
      bool valid = (e < en_g);
      ushort4 xu = (i==0) ? x0C : (i==1) ? x1C : (i==2) ? x2C : x3C;
      float x0=bf2f(xu.x), x1=bf2f(xu.y), x2=bf2f(xu.z), x3=bf2f(xu.w);
      float t0 = d0[i], t1 = d1[i], t2 = d2[i], t3 = d3[i];
      float part = att4.x*LEAKY(x0+xd0+t0);
      part = fmaf(att4.y, LEAKY(x1+xd1+t1), part);
      part = fmaf(att4.z, LEAKY(x2+xd2+t2), part);
      part = fmaf(att4.w, LEAKY(x3+xd3+t3), part);
      part += __shfl_xor(part, 1, 64);
      part += __shfl_xor(part, 2, 64);
      part += __shfl_xor(part, 4, 64);
      part += __shfl_xor(part, 8, 64);
      float c = valid ? part : -1e30f;
      float p = __expf(c);
      den += p;
      if (valid){ ts0 += t0; ts1 += t1; ts2 += t2; ts3 += t3; }
      ac0 = fmaf(p, x0, ac0); ac1 = fmaf(p, x1, ac1);
      ac2 = fmaf(p, x2, ac2); ac3 = fmaf(p, x3, ac3);
    }
    aC = aN;
    s0C=s0N; s1C=s1N; s2C=s2N; s3C=s3N;
    x0C=x0N; x1C=x1N; x2C=x2N; x3C=x3N;
  }
  // self loop: t_self = mean(t) by linearity; 0 for isolated nodes
  float inv = 1.f / fmaxf((float)deg, 1.f);
  float s0 = fmaf(ts0, inv, xd0 + xd0);
  float s1 = fmaf(ts1, inv, xd1 + xd1);
  float s2 = fmaf(ts2, inv, xd2 + xd2);
  float s3 = fmaf(ts3, inv, xd3 + xd3);
  float cs = att4.x*LEAKY(s0);
  cs = fmaf(att4.y, LEAKY(s1), cs);
  cs = fmaf(att4.z, LEAKY(s2), cs);
  cs = fmaf(att4.w, LEAKY(s3), cs);
  cs += __shfl_xor(cs, 1, 64);
  cs += __shfl_xor(cs, 2, 64);
  cs += __shfl_xor(cs, 4, 64);
  cs += __shfl_xor(cs, 8, 64);
  float ps = __expf(cs);
  den += ps;
  ac0 = fmaf(ps, xd0, ac0); ac1 = fmaf(ps, xd1, ac1);
  ac2 = fmaf(ps, xd2, ac2); ac3 = fmaf(ps, xd3, ac3);
  float4 o;
  float dinv = 1.f / den;
  o.x = fmaf(ac0, dinv, bi4.x);
  o.y = fmaf(ac1, dinv, bi4.y);
  o.z = fmaf(ac2, dinv, bi4.z);
  o.w = fmaf(ac3, dinv, bi4.w);
  *(float4*)(outp + (size_t)node_g*D + 4*q) = o;
}

extern "C" void kernel_launch(void* const* d_in, const int* in_sizes, int n_in,
                              void* d_out, int out_size, void* d_ws, size_t ws_size,
                              hipStream_t stream){
  const float* x     = (const float*)d_in[0];
  const int*   ei    = (const int*)d_in[1];
  const float* eattr = (const float*)d_in[2];
  const float* W1    = (const float*)d_in[3];
  const float* b1    = (const float*)d_in[4];
  const float* We1   = (const float*)d_in[5];
  const float* att1  = (const float*)d_in[6];
  const float* bias1 = (const float*)d_in[7];
  const float* W2    = (const float*)d_in[8];
  const float* b2    = (const float*)d_in[9];
  const float* We2   = (const float*)d_in[10];
  const float* att2  = (const float*)d_in[11];
  const float* bias2 = (const float*)d_in[12];
  const int* srcp = ei;
  const int* dstp = ei + NE;
  float* out = (float*)d_out;

  char* p = (char*)d_ws;
  size_t off = 0;
  auto alloc = [&](size_t bytes)->char*{
    char* r = p + off; off = (off + bytes + 255) & ~(size_t)255; return r;
  };
  int* cursor   = (int*)alloc((size_t)(NN+512)*4);   // deg + hist(256) + bincur(256)
  int* hist     = cursor + NN;
  int* bincur   = cursor + NN + 256;
  int* binoff   = (int*)alloc(256*4);
  int* rowptr   = (int*)alloc((size_t)(NN+1)*4);     // sorted-order CSR
  int* bsum     = (int*)alloc(512*4);
  int* rank     = (int*)alloc((size_t)NE*4);
  int* perm     = (int*)alloc((size_t)NN*4);
  int* nrank    = (int*)alloc((size_t)NN*4);
  int* degs     = (int*)alloc((size_t)NN*4);         // degree in sorted order
  int* ssrc     = (int*)alloc((size_t)NE*4);
  unsigned short* xl = (unsigned short*)alloc((size_t)NN*D*2);
  float* h      = (float*)alloc((size_t)NN*D*4);
  unsigned short* ea_csr = (unsigned short*)alloc((size_t)NE*DE*2);  // 102.4 MB

  hipMemsetAsync(cursor, 0, (size_t)(NN+512)*4, stream);
  k_deg     <<<(NE+255)/256, 256, 0, stream>>>(dstp, cursor, rank);
  k_hist    <<<NB_SCAN, 256, 0, stream>>>(cursor, hist);
  k_binscan <<<1, 256, 0, stream>>>(hist, binoff, bincur);
  k_sort    <<<NB_SCAN, 256, 0, stream>>>(cursor, bincur, perm, nrank, degs);
  k_scan_a  <<<NB_SCAN, 256, 0, stream>>>(degs, bsum);
  k_scan_b  <<<1, 512, 0, stream>>>(bsum, rowptr);
  k_scan_c  <<<NB_SCAN, 256, 0, stream>>>(bsum, rowptr, degs);
  k_scatter <<<NE/256, 256, 0, stream>>>(srcp, dstp, rank, nrank, rowptr, (const float4*)eattr, ssrc, ea_csr);

  // layer 1
  k_lin <<<1600, 256, 0, stream>>>(x, W1, b1, xl);
  k_node<<<6250, 256, 0, stream>>>(rowptr, perm, ssrc, ea_csr, We1, att1, xl, bias1, h);
  // layer 2
  k_lin <<<1600, 256, 0, stream>>>(h, W2, b2, xl);
  k_node<<<6250, 256, 0, stream>>>(rowptr, perm, ssrc, ea_csr, We2, att2, xl, bias2, out);
}

// Round 20
// 340.013 us; speedup vs baseline: 2.5281x; 2.5281x over previous
//
#include <hip/hip_runtime.h>
#include <math.h>

#define NN 100000
#define NE 1600000
#define D 64
#define DE 32
#define NB_SCAN ((NN + 255) / 256)   // 391

typedef __attribute__((ext_vector_type(8))) short short8;
typedef __attribute__((ext_vector_type(4))) float f32x4;

__device__ __forceinline__ int rfl(int v){ return __builtin_amdgcn_readfirstlane(v); }

#define LEAKY(v) fmaxf((v), 0.2f*(v))

__device__ __forceinline__ unsigned short f2bf(float x){
  unsigned u = __float_as_uint(x);
  unsigned r = (u + 0x7fffu + ((u >> 16) & 1u)) >> 16;
  return (unsigned short)r;
}
__device__ __forceinline__ float bf2f(unsigned short b){
  return __uint_as_float(((unsigned)b) << 16);
}

// deg accumulate AND per-edge rank harvest: rank[i] = old count of dst[i].
// Atomic return feeds a COALESCED write (no dependent random store).
__global__ __launch_bounds__(256) void k_deg(const int* __restrict__ dst, int* __restrict__ cursor,
                                             int* __restrict__ rank){
  int i = blockIdx.x*256 + threadIdx.x;
  if (i < NE) rank[i] = atomicAdd(&cursor[dst[i]], 1);
}

__global__ __launch_bounds__(256) void k_scan_a(const int* __restrict__ deg, int* __restrict__ bsum){
  __shared__ int sh[256];
  int tid = threadIdx.x;
  int i = blockIdx.x*256 + tid;
  sh[tid] = (i < NN) ? deg[i] : 0;
  __syncthreads();
  for (int s = 128; s > 0; s >>= 1){
    if (tid < s) sh[tid] += sh[tid+s];
    __syncthreads();
  }
  if (tid == 0) bsum[blockIdx.x] = sh[0];
}

__global__ __launch_bounds__(512) void k_scan_b(int* __restrict__ bsum, int* __restrict__ rowptr){
  __shared__ int tmp[512];
  int tid = threadIdx.x;
  int v = (tid < NB_SCAN) ? bsum[tid] : 0;
  tmp[tid] = v;
  __syncthreads();
  for (int off = 1; off < 512; off <<= 1){
    int t = (tid >= off) ? tmp[tid-off] : 0;
    __syncthreads();
    tmp[tid] += t;
    __syncthreads();
  }
  if (tid < NB_SCAN) bsum[tid] = tmp[tid] - v;
  if (tid == 511) rowptr[NN] = tmp[511];
}

// reads cursor (=deg), writes rowptr (exclusive offsets)
__global__ __launch_bounds__(256) void k_scan_c(const int* bsum, int* rowptr, const int* cursor){
  __shared__ int tmp[256];
  int tid = threadIdx.x;
  int i = blockIdx.x*256 + tid;
  int v = (i < NN) ? cursor[i] : 0;
  tmp[tid] = v;
  __syncthreads();
  for (int off = 1; off < 256; off <<= 1){
    int t = (tid >= off) ? tmp[tid-off] : 0;
    __syncthreads();
    tmp[tid] += t;
    __syncthreads();
  }
  if (i < NN){
    rowptr[i] = tmp[tid] - v + bsum[blockIdx.x];
  }
}

// Atomic-FREE scatter: pos = rowptr[dst] + rank (rowptr table is L2-resident).
// Then R15-proven block-cooperative copy: 8 threads/row read eattr COALESCED,
// write 64B bf16 row to ea_csr[pos]; ssrc[pos] = src.
__global__ __launch_bounds__(256) void k_scatter(const int* __restrict__ srcp, const int* __restrict__ dstp,
                                                 const int* __restrict__ rank, const int* __restrict__ rowptr,
                                                 const float4* __restrict__ eattr4,
                                                 int* __restrict__ ssrc,
                                                 unsigned short* __restrict__ ea_csr){
  __shared__ int spos[256];
  int tid = threadIdx.x;
  int i = blockIdx.x*256 + tid;
  int pos = 0;
  if (i < NE){
    int d = dstp[i];
    pos = rowptr[d] + rank[i];
    ssrc[pos] = srcp[i];
  }
  spos[tid] = pos;
  __syncthreads();
  int chunk = tid & 7;
  int rbase = blockIdx.x*256;
  #pragma unroll
  for (int k = 0; k < 8; ++k){
    int rl = (tid >> 3) + 32*k;
    int r = rbase + rl;
    if (r < NE){
      float4 v = eattr4[(size_t)r*8 + chunk];
      ushort4 o;
      o.x = f2bf(v.x); o.y = f2bf(v.y); o.z = f2bf(v.z); o.w = f2bf(v.w);
      *(ushort4*)(ea_csr + (size_t)spos[rl]*DE + chunk*4) = o;
    }
  }
}

// MFMA linear: xl[n][j] = bf16( b[j] + sum_k x[n][k]*W[k][j] ).
__global__ __launch_bounds__(256) void k_lin(const float* __restrict__ xin, const float* __restrict__ W,
                                             const float* __restrict__ b, unsigned short* __restrict__ xl){
  int lane = threadIdx.x & 63;
  int q = lane & 15, g = lane >> 4;
  int wid = blockIdx.x*(blockDim.x>>6) + (threadIdx.x>>6);
  int nw = gridDim.x*(blockDim.x>>6);
  short8 wb[2][4];
  #pragma unroll
  for (int kk = 0; kk < 2; ++kk)
    #pragma unroll
    for (int j = 0; j < 4; ++j)
      #pragma unroll
      for (int i = 0; i < 8; ++i)
        wb[kk][j][i] = (short)f2bf(W[(32*kk + 8*g + i)*D + 4*q + j]);
  float4 b4 = *(const float4*)(b + 4*q);
  for (int t0 = wid; t0 < NN/16; t0 += nw){
    int n0 = rfl(t0)*16;
    const float* xr = xin + (size_t)(n0 + q)*D + 8*g;
    float4 a0 = *(const float4*)(xr);
    float4 a1 = *(const float4*)(xr + 4);
    float4 a2 = *(const float4*)(xr + 32);
    float4 a3 = *(const float4*)(xr + 36);
    short8 af0, af1;
    af0[0]=(short)f2bf(a0.x); af0[1]=(short)f2bf(a0.y); af0[2]=(short)f2bf(a0.z); af0[3]=(short)f2bf(a0.w);
    af0[4]=(short)f2bf(a1.x); af0[5]=(short)f2bf(a1.y); af0[6]=(short)f2bf(a1.z); af0[7]=(short)f2bf(a1.w);
    af1[0]=(short)f2bf(a2.x); af1[1]=(short)f2bf(a2.y); af1[2]=(short)f2bf(a2.z); af1[3]=(short)f2bf(a2.w);
    af1[4]=(short)f2bf(a3.x); af1[5]=(short)f2bf(a3.y); af1[6]=(short)f2bf(a3.z); af1[7]=(short)f2bf(a3.w);
    f32x4 acc0 = {b4.x, b4.x, b4.x, b4.x};
    f32x4 acc1 = {b4.y, b4.y, b4.y, b4.y};
    f32x4 acc2 = {b4.z, b4.z, b4.z, b4.z};
    f32x4 acc3 = {b4.w, b4.w, b4.w, b4.w};
    acc0 = __builtin_amdgcn_mfma_f32_16x16x32_bf16(af0, wb[0][0], acc0, 0, 0, 0);
    acc1 = __builtin_amdgcn_mfma_f32_16x16x32_bf16(af0, wb[0][1], acc1, 0, 0, 0);
    acc2 = __builtin_amdgcn_mfma_f32_16x16x32_bf16(af0, wb[0][2], acc2, 0, 0, 0);
    acc3 = __builtin_amdgcn_mfma_f32_16x16x32_bf16(af0, wb[0][3], acc3, 0, 0, 0);
    acc0 = __builtin_amdgcn_mfma_f32_16x16x32_bf16(af1, wb[1][0], acc0, 0, 0, 0);
    acc1 = __builtin_amdgcn_mfma_f32_16x16x32_bf16(af1, wb[1][1], acc1, 0, 0, 0);
    acc2 = __builtin_amdgcn_mfma_f32_16x16x32_bf16(af1, wb[1][2], acc2, 0, 0, 0);
    acc3 = __builtin_amdgcn_mfma_f32_16x16x32_bf16(af1, wb[1][3], acc3, 0, 0, 0);
    #pragma unroll
    for (int i = 0; i < 4; ++i){
      ushort4 pk;
      pk.x = f2bf(acc0[i]); pk.y = f2bf(acc1[i]); pk.z = f2bf(acc2[i]); pk.w = f2bf(acc3[i]);
      *(ushort4*)(xl + (size_t)(n0 + 4*g + i)*D + 4*q) = pk;
    }
  }
}

// Fused layer, 4 NODES PER WAVE (one 16-lane group per node), software-
// pipelined: tile t+1's A-fragment, ssrc, and xl rows prefetch during tile t.
__global__ __launch_bounds__(256) void k_node(const int* __restrict__ rowptr,
                                              const int* __restrict__ ssrc,
                                              const unsigned short* __restrict__ ea_csr,
                                              const float* __restrict__ We,
                                              const float* __restrict__ att,
                                              const unsigned short* __restrict__ xl,
                                              const float* __restrict__ bias,
                                              float* __restrict__ outp){
  int lane = threadIdx.x & 63;
  int q = lane & 15, g = lane >> 4;
  int wid = blockIdx.x*(blockDim.x>>6) + (threadIdx.x>>6);
  int n0 = wid*4;                       // exact grid: 25000 waves x 4 nodes
  if (n0 >= NN) return;
  short8 wb[4];
  #pragma unroll
  for (int j = 0; j < 4; ++j)
    #pragma unroll
    for (int i = 0; i < 8; ++i)
      wb[j][i] = (short)f2bf(We[(8*g + i)*D + 4*q + j]);
  float4 att4 = *(const float4*)(att + 4*q);
  float4 bi4  = *(const float4*)(bias + 4*q);
  int st_g = rowptr[n0 + g], en_g = rowptr[n0 + g + 1];
  int anode = q >> 2, aoff = q & 3;
  int st_a = rowptr[n0 + anode], en_a = rowptr[n0 + anode + 1];
  int deg = en_g - st_g;
  int dmax = max(deg, __shfl_xor(deg, 16, 64));
  dmax = max(dmax, __shfl_xor(dmax, 32, 64));
  int ntile = (dmax + 3) >> 2;
  ushort4 xdu = *(const ushort4*)(xl + (size_t)(n0 + g)*D + 4*q);
  float xd0 = bf2f(xdu.x), xd1 = bf2f(xdu.y), xd2 = bf2f(xdu.z), xd3 = bf2f(xdu.w);
  float den = 0.f;
  float ac0=0.f, ac1=0.f, ac2=0.f, ac3=0.f;
  float ts0=0.f, ts1=0.f, ts2=0.f, ts3=0.f;

#define LOAD_A(T, DST) { int apos_ = st_a + (T)*4 + aoff; \
  int arow_ = (apos_ < en_a) ? apos_ : ((en_a > st_a) ? (en_a - 1) : 0); \
  DST = *(const short8*)(ea_csr + (size_t)arow_*DE + 8*g); }
#define LOAD_S(T, S0,S1,S2,S3) { int b_ = st_g + (T)*4; \
  S0 = ssrc[(b_   < en_g) ? b_   : 0]; S1 = ssrc[(b_+1 < en_g) ? b_+1 : 0]; \
  S2 = ssrc[(b_+2 < en_g) ? b_+2 : 0]; S3 = ssrc[(b_+3 < en_g) ? b_+3 : 0]; }
#define LOAD_X(S0,S1,S2,S3, X0,X1,X2,X3) { \
  X0 = *(const ushort4*)(xl + (size_t)S0*D + 4*q); \
  X1 = *(const ushort4*)(xl + (size_t)S1*D + 4*q); \
  X2 = *(const ushort4*)(xl + (size_t)S2*D + 4*q); \
  X3 = *(const ushort4*)(xl + (size_t)S3*D + 4*q); }

  short8 aC = {0,0,0,0,0,0,0,0};
  int s0C=0, s1C=0, s2C=0, s3C=0;
  ushort4 x0C={0,0,0,0}, x1C={0,0,0,0}, x2C={0,0,0,0}, x3C={0,0,0,0};
  if (ntile > 0){
    LOAD_A(0, aC);
    LOAD_S(0, s0C, s1C, s2C, s3C);
    LOAD_X(s0C, s1C, s2C, s3C, x0C, x1C, x2C, x3C);
  }
  for (int t = 0; t < ntile; ++t){
    short8 aN = aC;
    int s0N=s0C, s1N=s1C, s2N=s2C, s3N=s3C;
    ushort4 x0N=x0C, x1N=x1C, x2N=x2C, x3N=x3C;
    if (t + 1 < ntile){
      LOAD_A(t+1, aN);
      LOAD_S(t+1, s0N, s1N, s2N, s3N);
      LOAD_X(s0N, s1N, s2N, s3N, x0N, x1N, x2N, x3N);
    }
    __builtin_amdgcn_s_setprio(1);
    f32x4 d0={0.f,0.f,0.f,0.f}, d1={0.f,0.f,0.f,0.f}, d2={0.f,0.f,0.f,0.f}, d3={0.f,0.f,0.f,0.f};
    d0 = __builtin_amdgcn_mfma_f32_16x16x32_bf16(aC, wb[0], d0, 0, 0, 0);
    d1 = __builtin_amdgcn_mfma_f32_16x16x32_bf16(aC, wb[1], d1, 0, 0, 0);
    d2 = __builtin_amdgcn_mfma_f32_16x16x32_bf16(aC, wb[2], d2, 0, 0, 0);
    d3 = __builtin_amdgcn_mfma_f32_16x16x32_bf16(aC, wb[3], d3, 0, 0, 0);
    __builtin_amdgcn_s_setprio(0);
    #pragma unroll
    for (int i = 0; i < 4; ++i){
      int e = st_g + t*4 + i;
      bool valid = (e < en_g);
      ushort4 xu = (i==0) ? x0C : (i==1) ? x1C : (i==2) ? x2C : x3C;
      float x0=bf2f(xu.x), x1=bf2f(xu.y), x2=bf2f(xu.z), x3=bf2f(xu.w);
      float t0 = d0[i], t1 = d1[i], t2 = d2[i], t3 = d3[i];
      float part = att4.x*LEAKY(x0+xd0+t0);
      part = fmaf(att4.y, LEAKY(x1+xd1+t1), part);
      part = fmaf(att4.z, LEAKY(x2+xd2+t2), part);
      part = fmaf(att4.w, LEAKY(x3+xd3+t3), part);
      part += __shfl_xor(part, 1, 64);
      part += __shfl_xor(part, 2, 64);
      part += __shfl_xor(part, 4, 64);
      part += __shfl_xor(part, 8, 64);
      float c = valid ? part : -1e30f;
      float p = __expf(c);
      den += p;
      if (valid){ ts0 += t0; ts1 += t1; ts2 += t2; ts3 += t3; }
      ac0 = fmaf(p, x0, ac0); ac1 = fmaf(p, x1, ac1);
      ac2 = fmaf(p, x2, ac2); ac3 = fmaf(p, x3, ac3);
    }
    aC = aN;
    s0C=s0N; s1C=s1N; s2C=s2N; s3C=s3N;
    x0C=x0N; x1C=x1N; x2C=x2N; x3C=x3N;
  }
  // self loop: t_self = mean(t) by linearity; 0 for isolated nodes
  float inv = 1.f / fmaxf((float)deg, 1.f);
  float s0 = fmaf(ts0, inv, xd0 + xd0);
  float s1 = fmaf(ts1, inv, xd1 + xd1);
  float s2 = fmaf(ts2, inv, xd2 + xd2);
  float s3 = fmaf(ts3, inv, xd3 + xd3);
  float cs = att4.x*LEAKY(s0);
  cs = fmaf(att4.y, LEAKY(s1), cs);
  cs = fmaf(att4.z, LEAKY(s2), cs);
  cs = fmaf(att4.w, LEAKY(s3), cs);
  cs += __shfl_xor(cs, 1, 64);
  cs += __shfl_xor(cs, 2, 64);
  cs += __shfl_xor(cs, 4, 64);
  cs += __shfl_xor(cs, 8, 64);
  float ps = __expf(cs);
  den += ps;
  ac0 = fmaf(ps, xd0, ac0); ac1 = fmaf(ps, xd1, ac1);
  ac2 = fmaf(ps, xd2, ac2); ac3 = fmaf(ps, xd3, ac3);
  float4 o;
  float dinv = 1.f / den;
  o.x = fmaf(ac0, dinv, bi4.x);
  o.y = fmaf(ac1, dinv, bi4.y);
  o.z = fmaf(ac2, dinv, bi4.z);
  o.w = fmaf(ac3, dinv, bi4.w);
  *(float4*)(outp + (size_t)(n0 + g)*D + 4*q) = o;
}

extern "C" void kernel_launch(void* const* d_in, const int* in_sizes, int n_in,
                              void* d_out, int out_size, void* d_ws, size_t ws_size,
                              hipStream_t stream){
  const float* x     = (const float*)d_in[0];
  const int*   ei    = (const int*)d_in[1];
  const float* eattr = (const float*)d_in[2];
  const float* W1    = (const float*)d_in[3];
  const float* b1    = (const float*)d_in[4];
  const float* We1   = (const float*)d_in[5];
  const float* att1  = (const float*)d_in[6];
  const float* bias1 = (const float*)d_in[7];
  const float* W2    = (const float*)d_in[8];
  const float* b2    = (const float*)d_in[9];
  const float* We2   = (const float*)d_in[10];
  const float* att2  = (const float*)d_in[11];
  const float* bias2 = (const float*)d_in[12];
  const int* srcp = ei;
  const int* dstp = ei + NE;
  float* out = (float*)d_out;

  char* p = (char*)d_ws;
  size_t off = 0;
  auto alloc = [&](size_t bytes)->char*{
    char* r = p + off; off = (off + bytes + 255) & ~(size_t)255; return r;
  };
  int* rowptr   = (int*)alloc((size_t)(NN+1)*4);
  int* cursor   = (int*)alloc((size_t)NN*4);       // deg accumulator
  int* bsum     = (int*)alloc(512*4);
  int* rank     = (int*)alloc((size_t)NE*4);       // per-edge rank within dst
  int* ssrc     = (int*)alloc((size_t)NE*4);
  unsigned short* xl = (unsigned short*)alloc((size_t)NN*D*2);  // bf16 rows
  float* h      = (float*)alloc((size_t)NN*D*4);
  unsigned short* ea_csr = (unsigned short*)alloc((size_t)NE*DE*2);  // 102.4 MB bf16

  hipMemsetAsync(cursor, 0, (size_t)NN*4, stream);
  k_deg     <<<(NE+255)/256, 256, 0, stream>>>(dstp, cursor, rank);
  k_scan_a  <<<NB_SCAN, 256, 0, stream>>>(cursor, bsum);
  k_scan_b  <<<1, 512, 0, stream>>>(bsum, rowptr);
  k_scan_c  <<<NB_SCAN, 256, 0, stream>>>(bsum, rowptr, cursor);
  k_scatter <<<NE/256, 256, 0, stream>>>(srcp, dstp, rank, rowptr, (const float4*)eattr, ssrc, ea_csr);

  // layer 1
  k_lin <<<1600, 256, 0, stream>>>(x, W1, b1, xl);
  k_node<<<6250, 256, 0, stream>>>(rowptr, ssrc, ea_csr, We1, att1, xl, bias1, h);
  // layer 2
  k_lin <<<1600, 256, 0, stream>>>(h, W2, b2, xl);
  k_node<<<6250, 256, 0, stream>>>(rowptr, ssrc, ea_csr, We2, att2, xl, bias2, out);
}

// Round 21
// 333.515 us; speedup vs baseline: 2.5774x; 1.0195x over previous
//
#include <hip/hip_runtime.h>
#include <math.h>

#define NN 100000
#define NE 1600000
#define D 64
#define DE 32
#define NB_SCAN ((NN + 255) / 256)   // 391
#define NB_SCAT (NE/256)             // 6250
#define NB_LIN  1600

typedef __attribute__((ext_vector_type(8))) short short8;
typedef __attribute__((ext_vector_type(4))) float f32x4;

__device__ __forceinline__ int rfl(int v){ return __builtin_amdgcn_readfirstlane(v); }

#define LEAKY(v) fmaxf((v), 0.2f*(v))

__device__ __forceinline__ unsigned short f2bf(float x){
  unsigned u = __float_as_uint(x);
  unsigned r = (u + 0x7fffu + ((u >> 16) & 1u)) >> 16;
  return (unsigned short)r;
}
__device__ __forceinline__ float bf2f(unsigned short b){
  return __uint_as_float(((unsigned)b) << 16);
}

// deg accumulate AND per-edge rank harvest: rank[i] = old count of dst[i].
__global__ __launch_bounds__(256) void k_deg(const int* __restrict__ dst, int* __restrict__ cursor,
                                             int* __restrict__ rank){
  int i = blockIdx.x*256 + threadIdx.x;
  if (i < NE) rank[i] = atomicAdd(&cursor[dst[i]], 1);
}

__global__ __launch_bounds__(256) void k_scan_a(const int* __restrict__ deg, int* __restrict__ bsum){
  __shared__ int sh[256];
  int tid = threadIdx.x;
  int i = blockIdx.x*256 + tid;
  sh[tid] = (i < NN) ? deg[i] : 0;
  __syncthreads();
  for (int s = 128; s > 0; s >>= 1){
    if (tid < s) sh[tid] += sh[tid+s];
    __syncthreads();
  }
  if (tid == 0) bsum[blockIdx.x] = sh[0];
}

__global__ __launch_bounds__(512) void k_scan_b(int* __restrict__ bsum, int* __restrict__ rowptr){
  __shared__ int tmp[512];
  int tid = threadIdx.x;
  int v = (tid < NB_SCAN) ? bsum[tid] : 0;
  tmp[tid] = v;
  __syncthreads();
  for (int off = 1; off < 512; off <<= 1){
    int t = (tid >= off) ? tmp[tid-off] : 0;
    __syncthreads();
    tmp[tid] += t;
    __syncthreads();
  }
  if (tid < NB_SCAN) bsum[tid] = tmp[tid] - v;
  if (tid == 511) rowptr[NN] = tmp[511];
}

__global__ __launch_bounds__(256) void k_scan_c(const int* bsum, int* rowptr, const int* cursor){
  __shared__ int tmp[256];
  int tid = threadIdx.x;
  int i = blockIdx.x*256 + tid;
  int v = (i < NN) ? cursor[i] : 0;
  tmp[tid] = v;
  __syncthreads();
  for (int off = 1; off < 256; off <<= 1){
    int t = (tid >= off) ? tmp[tid-off] : 0;
    __syncthreads();
    tmp[tid] += t;
    __syncthreads();
  }
  if (i < NN){
    rowptr[i] = tmp[tid] - v + bsum[blockIdx.x];
  }
}

// Heterogeneous dispatch: blocks [0,NB_SCAT) = atomic-free scatter (R18 body);
// blocks [NB_SCAT, NB_SCAT+NB_LIN) = layer-1 MFMA linear (R18 body).
// The two are data-independent; lin compute fills the scatter's latency shadow.
__global__ __launch_bounds__(256) void k_scat_lin(const int* __restrict__ srcp, const int* __restrict__ dstp,
                                                  const int* __restrict__ rank, const int* __restrict__ rowptr,
                                                  const float4* __restrict__ eattr4,
                                                  int* __restrict__ ssrc,
                                                  unsigned short* __restrict__ ea_csr,
                                                  const float* __restrict__ xin, const float* __restrict__ W,
                                                  const float* __restrict__ b, unsigned short* __restrict__ xl){
  if (blockIdx.x < NB_SCAT){
    // ---- scatter body (verbatim R18) ----
    __shared__ int spos[256];
    int tid = threadIdx.x;
    int i = blockIdx.x*256 + tid;
    int pos = 0;
    if (i < NE){
      int d = dstp[i];
      pos = rowptr[d] + rank[i];
      ssrc[pos] = srcp[i];
    }
    spos[tid] = pos;
    __syncthreads();
    int chunk = tid & 7;
    int rbase = blockIdx.x*256;
    #pragma unroll
    for (int k = 0; k < 8; ++k){
      int rl = (tid >> 3) + 32*k;
      int r = rbase + rl;
      if (r < NE){
        float4 v = eattr4[(size_t)r*8 + chunk];
        ushort4 o;
        o.x = f2bf(v.x); o.y = f2bf(v.y); o.z = f2bf(v.z); o.w = f2bf(v.w);
        *(ushort4*)(ea_csr + (size_t)spos[rl]*DE + chunk*4) = o;
      }
    }
  } else {
    // ---- k_lin body (verbatim R18, grid-strided over its block range) ----
    int lane = threadIdx.x & 63;
    int q = lane & 15, g = lane >> 4;
    int bid = blockIdx.x - NB_SCAT;
    int wid = bid*4 + (threadIdx.x>>6);
    int nw = NB_LIN*4;
    short8 wb[2][4];
    #pragma unroll
    for (int kk = 0; kk < 2; ++kk)
      #pragma unroll
      for (int j = 0; j < 4; ++j)
        #pragma unroll
        for (int i = 0; i < 8; ++i)
          wb[kk][j][i] = (short)f2bf(W[(32*kk + 8*g + i)*D + 4*q + j]);
    float4 b4 = *(const float4*)(b + 4*q);
    for (int t0 = wid; t0 < NN/16; t0 += nw){
      int n0 = rfl(t0)*16;
      const float* xr = xin + (size_t)(n0 + q)*D + 8*g;
      float4 a0 = *(const float4*)(xr);
      float4 a1 = *(const float4*)(xr + 4);
      float4 a2 = *(const float4*)(xr + 32);
      float4 a3 = *(const float4*)(xr + 36);
      short8 af0, af1;
      af0[0]=(short)f2bf(a0.x); af0[1]=(short)f2bf(a0.y); af0[2]=(short)f2bf(a0.z); af0[3]=(short)f2bf(a0.w);
      af0[4]=(short)f2bf(a1.x); af0[5]=(short)f2bf(a1.y); af0[6]=(short)f2bf(a1.z); af0[7]=(short)f2bf(a1.w);
      af1[0]=(short)f2bf(a2.x); af1[1]=(short)f2bf(a2.y); af1[2]=(short)f2bf(a2.z); af1[3]=(short)f2bf(a2.w);
      af1[4]=(short)f2bf(a3.x); af1[5]=(short)f2bf(a3.y); af1[6]=(short)f2bf(a3.z); af1[7]=(short)f2bf(a3.w);
      f32x4 acc0 = {b4.x, b4.x, b4.x, b4.x};
      f32x4 acc1 = {b4.y, b4.y, b4.y, b4.y};
      f32x4 acc2 = {b4.z, b4.z, b4.z, b4.z};
      f32x4 acc3 = {b4.w, b4.w, b4.w, b4.w};
      acc0 = __builtin_amdgcn_mfma_f32_16x16x32_bf16(af0, wb[0][0], acc0, 0, 0, 0);
      acc1 = __builtin_amdgcn_mfma_f32_16x16x32_bf16(af0, wb[0][1], acc1, 0, 0, 0);
      acc2 = __builtin_amdgcn_mfma_f32_16x16x32_bf16(af0, wb[0][2], acc2, 0, 0, 0);
      acc3 = __builtin_amdgcn_mfma_f32_16x16x32_bf16(af0, wb[0][3], acc3, 0, 0, 0);
      acc0 = __builtin_amdgcn_mfma_f32_16x16x32_bf16(af1, wb[1][0], acc0, 0, 0, 0);
      acc1 = __builtin_amdgcn_mfma_f32_16x16x32_bf16(af1, wb[1][1], acc1, 0, 0, 0);
      acc2 = __builtin_amdgcn_mfma_f32_16x16x32_bf16(af1, wb[1][2], acc2, 0, 0, 0);
      acc3 = __builtin_amdgcn_mfma_f32_16x16x32_bf16(af1, wb[1][3], acc3, 0, 0, 0);
      #pragma unroll
      for (int i = 0; i < 4; ++i){
        ushort4 pk;
        pk.x = f2bf(acc0[i]); pk.y = f2bf(acc1[i]); pk.z = f2bf(acc2[i]); pk.w = f2bf(acc3[i]);
        *(ushort4*)(xl + (size_t)(n0 + 4*g + i)*D + 4*q) = pk;
      }
    }
  }
}

// MFMA linear: xl[n][j] = bf16( b[j] + sum_k x[n][k]*W[k][j] ).
__global__ __launch_bounds__(256) void k_lin(const float* __restrict__ xin, const float* __restrict__ W,
                                             const float* __restrict__ b, unsigned short* __restrict__ xl){
  int lane = threadIdx.x & 63;
  int q = lane & 15, g = lane >> 4;
  int wid = blockIdx.x*(blockDim.x>>6) + (threadIdx.x>>6);
  int nw = gridDim.x*(blockDim.x>>6);
  short8 wb[2][4];
  #pragma unroll
  for (int kk = 0; kk < 2; ++kk)
    #pragma unroll
    for (int j = 0; j < 4; ++j)
      #pragma unroll
      for (int i = 0; i < 8; ++i)
        wb[kk][j][i] = (short)f2bf(W[(32*kk + 8*g + i)*D + 4*q + j]);
  float4 b4 = *(const float4*)(b + 4*q);
  for (int t0 = wid; t0 < NN/16; t0 += nw){
    int n0 = rfl(t0)*16;
    const float* xr = xin + (size_t)(n0 + q)*D + 8*g;
    float4 a0 = *(const float4*)(xr);
    float4 a1 = *(const float4*)(xr + 4);
    float4 a2 = *(const float4*)(xr + 32);
    float4 a3 = *(const float4*)(xr + 36);
    short8 af0, af1;
    af0[0]=(short)f2bf(a0.x); af0[1]=(short)f2bf(a0.y); af0[2]=(short)f2bf(a0.z); af0[3]=(short)f2bf(a0.w);
    af0[4]=(short)f2bf(a1.x); af0[5]=(short)f2bf(a1.y); af0[6]=(short)f2bf(a1.z); af0[7]=(short)f2bf(a1.w);
    af1[0]=(short)f2bf(a2.x); af1[1]=(short)f2bf(a2.y); af1[2]=(short)f2bf(a2.z); af1[3]=(short)f2bf(a2.w);
    af1[4]=(short)f2bf(a3.x); af1[5]=(short)f2bf(a3.y); af1[6]=(short)f2bf(a3.z); af1[7]=(short)f2bf(a3.w);
    f32x4 acc0 = {b4.x, b4.x, b4.x, b4.x};
    f32x4 acc1 = {b4.y, b4.y, b4.y, b4.y};
    f32x4 acc2 = {b4.z, b4.z, b4.z, b4.z};
    f32x4 acc3 = {b4.w, b4.w, b4.w, b4.w};
    acc0 = __builtin_amdgcn_mfma_f32_16x16x32_bf16(af0, wb[0][0], acc0, 0, 0, 0);
    acc1 = __builtin_amdgcn_mfma_f32_16x16x32_bf16(af0, wb[0][1], acc1, 0, 0, 0);
    acc2 = __builtin_amdgcn_mfma_f32_16x16x32_bf16(af0, wb[0][2], acc2, 0, 0, 0);
    acc3 = __builtin_amdgcn_mfma_f32_16x16x32_bf16(af0, wb[0][3], acc3, 0, 0, 0);
    acc0 = __builtin_amdgcn_mfma_f32_16x16x32_bf16(af1, wb[1][0], acc0, 0, 0, 0);
    acc1 = __builtin_amdgcn_mfma_f32_16x16x32_bf16(af1, wb[1][1], acc1, 0, 0, 0);
    acc2 = __builtin_amdgcn_mfma_f32_16x16x32_bf16(af1, wb[1][2], acc2, 0, 0, 0);
    acc3 = __builtin_amdgcn_mfma_f32_16x16x32_bf16(af1, wb[1][3], acc3, 0, 0, 0);
    #pragma unroll
    for (int i = 0; i < 4; ++i){
      ushort4 pk;
      pk.x = f2bf(acc0[i]); pk.y = f2bf(acc1[i]); pk.z = f2bf(acc2[i]); pk.w = f2bf(acc3[i]);
      *(ushort4*)(xl + (size_t)(n0 + 4*g + i)*D + 4*q) = pk;
    }
  }
}

// Fused layer, 4 NODES PER WAVE (one 16-lane group per node), software-
// pipelined: tile t+1's A-fragment, ssrc, and xl rows prefetch during tile t.
__global__ __launch_bounds__(256) void k_node(const int* __restrict__ rowptr,
                                              const int* __restrict__ ssrc,
                                              const unsigned short* __restrict__ ea_csr,
                                              const float* __restrict__ We,
                                              const float* __restrict__ att,
                                              const unsigned short* __restrict__ xl,
                                              const float* __restrict__ bias,
                                              float* __restrict__ outp){
  int lane = threadIdx.x & 63;
  int q = lane & 15, g = lane >> 4;
  int wid = blockIdx.x*(blockDim.x>>6) + (threadIdx.x>>6);
  int n0 = wid*4;
  if (n0 >= NN) return;
  short8 wb[4];
  #pragma unroll
  for (int j = 0; j < 4; ++j)
    #pragma unroll
    for (int i = 0; i < 8; ++i)
      wb[j][i] = (short)f2bf(We[(8*g + i)*D + 4*q + j]);
  float4 att4 = *(const float4*)(att + 4*q);
  float4 bi4  = *(const float4*)(bias + 4*q);
  int st_g = rowptr[n0 + g], en_g = rowptr[n0 + g + 1];
  int anode = q >> 2, aoff = q & 3;
  int st_a = rowptr[n0 + anode], en_a = rowptr[n0 + anode + 1];
  int deg = en_g - st_g;
  int dmax = max(deg, __shfl_xor(deg, 16, 64));
  dmax = max(dmax, __shfl_xor(dmax, 32, 64));
  int ntile = (dmax + 3) >> 2;
  ushort4 xdu = *(const ushort4*)(xl + (size_t)(n0 + g)*D + 4*q);
  float xd0 = bf2f(xdu.x), xd1 = bf2f(xdu.y), xd2 = bf2f(xdu.z), xd3 = bf2f(xdu.w);
  float den = 0.f;
  float ac0=0.f, ac1=0.f, ac2=0.f, ac3=0.f;
  float ts0=0.f, ts1=0.f, ts2=0.f, ts3=0.f;

#define LOAD_A(T, DST) { int apos_ = st_a + (T)*4 + aoff; \
  int arow_ = (apos_ < en_a) ? apos_ : ((en_a > st_a) ? (en_a - 1) : 0); \
  DST = *(const short8*)(ea_csr + (size_t)arow_*DE + 8*g); }
#define LOAD_S(T, S0,S1,S2,S3) { int b_ = st_g + (T)*4; \
  S0 = ssrc[(b_   < en_g) ? b_   : 0]; S1 = ssrc[(b_+1 < en_g) ? b_+1 : 0]; \
  S2 = ssrc[(b_+2 < en_g) ? b_+2 : 0]; S3 = ssrc[(b_+3 < en_g) ? b_+3 : 0]; }
#define LOAD_X(S0,S1,S2,S3, X0,X1,X2,X3) { \
  X0 = *(const ushort4*)(xl + (size_t)S0*D + 4*q); \
  X1 = *(const ushort4*)(xl + (size_t)S1*D + 4*q); \
  X2 = *(const ushort4*)(xl + (size_t)S2*D + 4*q); \
  X3 = *(const ushort4*)(xl + (size_t)S3*D + 4*q); }

  short8 aC = {0,0,0,0,0,0,0,0};
  int s0C=0, s1C=0, s2C=0, s3C=0;
  ushort4 x0C={0,0,0,0}, x1C={0,0,0,0}, x2C={0,0,0,0}, x3C={0,0,0,0};
  if (ntile > 0){
    LOAD_A(0, aC);
    LOAD_S(0, s0C, s1C, s2C, s3C);
    LOAD_X(s0C, s1C, s2C, s3C, x0C, x1C, x2C, x3C);
  }
  for (int t = 0; t < ntile; ++t){
    short8 aN = aC;
    int s0N=s0C, s1N=s1C, s2N=s2C, s3N=s3C;
    ushort4 x0N=x0C, x1N=x1C, x2N=x2C, x3N=x3C;
    if (t + 1 < ntile){
      LOAD_A(t+1, aN);
      LOAD_S(t+1, s0N, s1N, s2N, s3N);
      LOAD_X(s0N, s1N, s2N, s3N, x0N, x1N, x2N, x3N);
    }
    __builtin_amdgcn_s_setprio(1);
    f32x4 d0={0.f,0.f,0.f,0.f}, d1={0.f,0.f,0.f,0.f}, d2={0.f,0.f,0.f,0.f}, d3={0.f,0.f,0.f,0.f};
    d0 = __builtin_amdgcn_mfma_f32_16x16x32_bf16(aC, wb[0], d0, 0, 0, 0);
    d1 = __builtin_amdgcn_mfma_f32_16x16x32_bf16(aC, wb[1], d1, 0, 0, 0);
    d2 = __builtin_amdgcn_mfma_f32_16x16x32_bf16(aC, wb[2], d2, 0, 0, 0);
    d3 = __builtin_amdgcn_mfma_f32_16x16x32_bf16(aC, wb[3], d3, 0, 0, 0);
    __builtin_amdgcn_s_setprio(0);
    #pragma unroll
    for (int i = 0; i < 4; ++i){
      int e = st_g + t*4 + i;
      bool valid = (e < en_g);
      ushort4 xu = (i==0) ? x0C : (i==1) ? x1C : (i==2) ? x2C : x3C;
      float x0=bf2f(xu.x), x1=bf2f(xu.y), x2=bf2f(xu.z), x3=bf2f(xu.w);
      float t0 = d0[i], t1 = d1[i], t2 = d2[i], t3 = d3[i];
      float part = att4.x*LEAKY(x0+xd0+t0);
      part = fmaf(att4.y, LEAKY(x1+xd1+t1), part);
      part = fmaf(att4.z, LEAKY(x2+xd2+t2), part);
      part = fmaf(att4.w, LEAKY(x3+xd3+t3), part);
      part += __shfl_xor(part, 1, 64);
      part += __shfl_xor(part, 2, 64);
      part += __shfl_xor(part, 4, 64);
      part += __shfl_xor(part, 8, 64);
      float c = valid ? part : -1e30f;
      float p = __expf(c);
      den += p;
      if (valid){ ts0 += t0; ts1 += t1; ts2 += t2; ts3 += t3; }
      ac0 = fmaf(p, x0, ac0); ac1 = fmaf(p, x1, ac1);
      ac2 = fmaf(p, x2, ac2); ac3 = fmaf(p, x3, ac3);
    }
    aC = aN;
    s0C=s0N; s1C=s1N; s2C=s2N; s3C=s3N;
    x0C=x0N; x1C=x1N; x2C=x2N; x3C=x3N;
  }
  float inv = 1.f / fmaxf((float)deg, 1.f);
  float s0 = fmaf(ts0, inv, xd0 + xd0);
  float s1 = fmaf(ts1, inv, xd1 + xd1);
  float s2 = fmaf(ts2, inv, xd2 + xd2);
  float s3 = fmaf(ts3, inv, xd3 + xd3);
  float cs = att4.x*LEAKY(s0);
  cs = fmaf(att4.y, LEAKY(s1), cs);
  cs = fmaf(att4.z, LEAKY(s2), cs);
  cs = fmaf(att4.w, LEAKY(s3), cs);
  cs += __shfl_xor(cs, 1, 64);
  cs += __shfl_xor(cs, 2, 64);
  cs += __shfl_xor(cs, 4, 64);
  cs += __shfl_xor(cs, 8, 64);
  float ps = __expf(cs);
  den += ps;
  ac0 = fmaf(ps, xd0, ac0); ac1 = fmaf(ps, xd1, ac1);
  ac2 = fmaf(ps, xd2, ac2); ac3 = fmaf(ps, xd3, ac3);
  float4 o;
  float dinv = 1.f / den;
  o.x = fmaf(ac0, dinv, bi4.x);
  o.y = fmaf(ac1, dinv, bi4.y);
  o.z = fmaf(ac2, dinv, bi4.z);
  o.w = fmaf(ac3, dinv, bi4.w);
  *(float4*)(outp + (size_t)(n0 + g)*D + 4*q) = o;
}

extern "C" void kernel_launch(void* const* d_in, const int* in_sizes, int n_in,
                              void* d_out, int out_size, void* d_ws, size_t ws_size,
                              hipStream_t stream){
  const float* x     = (const float*)d_in[0];
  const int*   ei    = (const int*)d_in[1];
  const float* eattr = (const float*)d_in[2];
  const float* W1    = (const float*)d_in[3];
  const float* b1    = (const float*)d_in[4];
  const float* We1   = (const float*)d_in[5];
  const float* att1  = (const float*)d_in[6];
  const float* bias1 = (const float*)d_in[7];
  const float* W2    = (const float*)d_in[8];
  const float* b2    = (const float*)d_in[9];
  const float* We2   = (const float*)d_in[10];
  const float* att2  = (const float*)d_in[11];
  const float* bias2 = (const float*)d_in[12];
  const int* srcp = ei;
  const int* dstp = ei + NE;
  float* out = (float*)d_out;

  char* p = (char*)d_ws;
  size_t off = 0;
  auto alloc = [&](size_t bytes)->char*{
    char* r = p + off; off = (off + bytes + 255) & ~(size_t)255; return r;
  };
  int* rowptr   = (int*)alloc((size_t)(NN+1)*4);
  int* cursor   = (int*)alloc((size_t)NN*4);       // deg accumulator
  int* bsum     = (int*)alloc(512*4);
  int* rank     = (int*)alloc((size_t)NE*4);       // per-edge rank within dst
  int* ssrc     = (int*)alloc((size_t)NE*4);
  unsigned short* xl = (unsigned short*)alloc((size_t)NN*D*2);  // bf16 rows
  float* h      = (float*)alloc((size_t)NN*D*4);
  unsigned short* ea_csr = (unsigned short*)alloc((size_t)NE*DE*2);  // 102.4 MB bf16

  hipMemsetAsync(cursor, 0, (size_t)NN*4, stream);
  k_deg     <<<(NE+255)/256, 256, 0, stream>>>(dstp, cursor, rank);
  k_scan_a  <<<NB_SCAN, 256, 0, stream>>>(cursor, bsum);
  k_scan_b  <<<1, 512, 0, stream>>>(bsum, rowptr);
  k_scan_c  <<<NB_SCAN, 256, 0, stream>>>(bsum, rowptr, cursor);

  // fused: CSR build (scatter) + layer-1 linear, data-independent halves
  k_scat_lin<<<NB_SCAT + NB_LIN, 256, 0, stream>>>(srcp, dstp, rank, rowptr, (const float4*)eattr,
                                                   ssrc, ea_csr, x, W1, b1, xl);

  // layer 1 aggregate
  k_node<<<6250, 256, 0, stream>>>(rowptr, ssrc, ea_csr, We1, att1, xl, bias1, h);
  // layer 2
  k_lin <<<1600, 256, 0, stream>>>(h, W2, b2, xl);
  k_node<<<6250, 256, 0, stream>>>(rowptr, ssrc, ea_csr, We2, att2, xl, bias2, out);
}